// Round 13
// baseline (191.185 us; speedup 1.0000x reference)
//
#include <hip/hip_runtime.h>
#include <hip/hip_bf16.h>

// FeatureProcessingBlock: per 64x64 window, Out = sum_t Cs_t^T ( Hs_t^T @ X_c @ Ws_t )
// R13 = R12 with the missing half-slot offset fixed: B(v) writes Zb at byte
//     4*cp + 8*(v&1)  (sub-chunk v covers channels 4v..4v+3 -> slot half v&1).
// Structure: Zb t-lines [dbuf][3t][1024px][16B] (C-reads linear b128), sub-chunk
//     pipeline {B(v); A(v+1); C every 2nd} | bar, Y1F dbuf by v-parity,
//     Zb dbuf by chunk-parity. 12 barriers/window.

typedef __attribute__((ext_vector_type(8))) short short8;
typedef __attribute__((ext_vector_type(4))) short short4v;
typedef __attribute__((ext_vector_type(4))) float float4v;

#define SMEM_BYTES 161296
// Y1F @0: [2 u][12 (t*4+cl)][2 sv][64 lane][16B] = 49152
// Zb @49152: [2 sb][3 t][1024 px][16B] = 98304   (slot k=t*8+c at line t byte 2c)
// Cf @147456: [18 ss*m][16 lc][48B] = 13824 | z16 @161280: 16B zeros

static __device__ __forceinline__ unsigned short f2bf(float f) {
  return __builtin_bit_cast(unsigned short, __float2bfloat16(f));
}
static __device__ __forceinline__ unsigned int pk2(float a, float b) {
  return (unsigned int)f2bf(a) | ((unsigned int)f2bf(b) << 16);
}
// LDS-only barrier: orders ds ops, leaves global loads in flight (T4).
static __device__ __forceinline__ void wg_barrier_lds() {
  asm volatile("s_waitcnt lgkmcnt(0)" ::: "memory");
  __builtin_amdgcn_s_barrier();
  asm volatile("" ::: "memory");
}

__global__ __launch_bounds__(512, 2)
void fpb13(const float* __restrict__ x, const float* __restrict__ Ws,
           const float* __restrict__ Hsm, const float* __restrict__ Cs,
           float* __restrict__ out) {
  extern __shared__ char smem[];
  char* Y1F = smem;                 // + (v&1)*24576
  char* Zb  = smem + 49152;         // + ((v>>1)&1)*49152
  char* Cf  = smem + 147456;
  char* z16 = smem + 161280;

  int wid = (blockIdx.x & 7) * 128 + (blockIdx.x >> 3);  // XCD swizzle
  int window = wid >> 2, tile = wid & 3;
  int b = window >> 6, p = (window >> 3) & 7, q = window & 7;
  int j0 = tile * 16;

  int tid = threadIdx.x, lane = tid & 63, wave = tid >> 6;
  int lq = lane >> 4, lc = lane & 15;
  int clA = wave & 3, hh = wave >> 2;   // A roles: c-local, mA half (mA=2hh+j2)
  int mt  = wave & 3, cp = wave >> 2;   // B roles: H'-tile, c-pair (cl=2cp+cj)

  if (tid < 4) ((unsigned int*)z16)[tid] = 0;

  // Cf init: row (ss*3+m, lc); k=t*8+c -> lane lq holds t=lq, e=c (chunk channel)
  for (int idx = wave; idx < 18; idx += 8) {
    int ss = idx / 3, m = idx - 3 * ss;
    if (lq < 3) {
      short8 v;
      #pragma unroll
      for (int e = 0; e < 8; ++e)
        v[e] = (short)f2bf(Cs[lq * 2304 + (8 * ss + e) * 48 + 16 * m + lc]);
      *(short8*)(Cf + (idx * 16 + lc) * 48 + lq * 16) = v;
    }
  }

  // persistent factor fragments (identical R11)
  short8 wsf[3][2], hsf[3][2];
  #pragma unroll
  for (int t = 0; t < 3; ++t)
    #pragma unroll
    for (int sv = 0; sv < 2; ++sv) {
      short8 aa, bb;
      #pragma unroll
      for (int e = 0; e < 8; ++e) {
        int k = 32 * sv + 8 * lq + e;
        aa[e] = (short)f2bf(Ws [t * 4096 + k * 64 + j0 + lc]);      // B: Ws[w][W']
        bb[e] = (short)f2bf(Hsm[t * 4096 + k * 64 + 16 * mt + lc]); // A: Hs^T[H'][h]
      }
      wsf[t][sv] = aa; hsf[t][sv] = bb;
    }

  float4v acc[3][8];
  #pragma unroll
  for (int m = 0; m < 3; ++m)
    #pragma unroll
    for (int i = 0; i < 8; ++i) acc[m][i] = float4v{0.f, 0.f, 0.f, 0.f};

  // A staging base: c = 4v + clA; rows 16*mA+lc = 32hh + 16j2 + lc; cols 8lq(+32)
  const float* xA = x + (((size_t)b * 48) * 512 + p * 64) * 512 + q * 64
                      + (size_t)clA * 262144 + (size_t)(32 * hh + lc) * 512 + 8 * lq;

  float4v fin[8];
  #define LOADFIN(vv) do {                                        \
    const float* srcb_ = xA + (size_t)(vv) * 1048576;             \
    _Pragma("unroll")                                             \
    for (int j2_ = 0; j2_ < 2; ++j2_) {                           \
      const float* r_ = srcb_ + (size_t)j2_ * 8192;               \
      fin[4*j2_+0] = *(const float4v*)(r_);                       \
      fin[4*j2_+1] = *(const float4v*)(r_ + 4);                   \
      fin[4*j2_+2] = *(const float4v*)(r_ + 32);                  \
      fin[4*j2_+3] = *(const float4v*)(r_ + 36);                  \
    }                                                             \
  } while (0)

  // ---- A block: sub-chunk v -> Y1F[v&1] (frag-major store, R5/R11-verified) ----
  #define ABLOCK(vv) do {                                                     \
    char* yb_ = Y1F + ((vv) & 1) * 24576;                                     \
    short8 af_[4];                                                            \
    _Pragma("unroll")                                                         \
    for (int j2_ = 0; j2_ < 2; ++j2_) {                                       \
      short8 a0_, a1_;                                                        \
      _Pragma("unroll")                                                       \
      for (int e2_ = 0; e2_ < 4; ++e2_) {                                     \
        a0_[e2_]   = (short)f2bf(fin[4*j2_+0][e2_]);                          \
        a0_[4+e2_] = (short)f2bf(fin[4*j2_+1][e2_]);                          \
        a1_[e2_]   = (short)f2bf(fin[4*j2_+2][e2_]);                          \
        a1_[4+e2_] = (short)f2bf(fin[4*j2_+3][e2_]);                          \
      }                                                                       \
      af_[2*j2_] = a0_; af_[2*j2_+1] = a1_;                                   \
    }                                                                         \
    if ((vv) < 11) LOADFIN((vv) + 1);                                         \
    _Pragma("unroll")                                                         \
    for (int j2_ = 0; j2_ < 2; ++j2_) {                                       \
      int mA_  = 2 * hh + j2_;                                                \
      int sv_  = mA_ >> 1;                                                    \
      int lqp_ = (2 * mA_ + (lq >> 1)) & 3;                                   \
      int eo_  = (lq & 1) * 8;                                                \
      _Pragma("unroll")                                                       \
      for (int t_ = 0; t_ < 3; ++t_) {                                        \
        float4v d_ = {0.f, 0.f, 0.f, 0.f};                                    \
        d_ = __builtin_amdgcn_mfma_f32_16x16x32_bf16(af_[2*j2_],   wsf[t_][0], d_, 0, 0, 0); \
        d_ = __builtin_amdgcn_mfma_f32_16x16x32_bf16(af_[2*j2_+1], wsf[t_][1], d_, 0, 0, 0); \
        short4v pv_;                                                          \
        pv_[0] = (short)f2bf(d_[0]); pv_[1] = (short)f2bf(d_[1]);             \
        pv_[2] = (short)f2bf(d_[2]); pv_[3] = (short)f2bf(d_[3]);             \
        *(short4v*)(yb_ + ((t_ * 4 + clA) * 2 + sv_) * 1024                   \
                        + (lqp_ * 16 + lc) * 16 + eo_) = pv_;                 \
      }                                                                       \
    }                                                                         \
  } while (0)

  LOADFIN(0);
  wg_barrier_lds();     // Cf/z16 init visible
  ABLOCK(0);
  wg_barrier_lds();     // Y1F[0] ready for B(0)

  #pragma unroll 1
  for (int v = 0; v < 12; ++v) {
    // ---- B(v): Y1F[v&1] -> Zb[(v>>1)&1], slot half (v&1)  (contract h) ----
    {
      const char* yb = Y1F + (v & 1) * 24576;
      char* zb = Zb + ((v >> 1) & 1) * 49152;
      int half = (v & 1) * 8;                     // THE R12 FIX
      #pragma unroll
      for (int t = 0; t < 3; ++t) {
        float4v dB[2];
        #pragma unroll
        for (int cj = 0; cj < 2; ++cj) {
          int cl = 2 * cp + cj;
          const char* ybs = yb + ((t * 4 + cl) * 2) * 1024 + lane * 16;
          short8 y0 = *(const short8*)ybs;
          short8 y1 = *(const short8*)(ybs + 1024);
          float4v dd = {0.f, 0.f, 0.f, 0.f};
          dd = __builtin_amdgcn_mfma_f32_16x16x32_bf16(hsf[t][0], y0, dd, 0, 0, 0);
          dd = __builtin_amdgcn_mfma_f32_16x16x32_bf16(hsf[t][1], y1, dd, 0, 0, 0);
          dB[cj] = dd;
        }
        #pragma unroll
        for (int r = 0; r < 4; ++r) {
          int px = (16 * mt + 4 * lq + r) * 16 + lc;
          *(unsigned int*)(zb + t * 16384 + px * 16 + half + 4 * cp) =
              pk2(dB[0][r], dB[1][r]);
        }
      }
    }
    // ---- A(v+1): next sub-chunk into Y1F[(v+1)&1] (overlaps B's LDS chain) ----
    if (v < 11) ABLOCK(v + 1);
    // ---- C(S-1): every second region, reads Zb[(S-1)&1] (other buffer) ----
    if ((v & 1) && v >= 3) {
      int Sp = (v >> 1) - 1;
      const char* zb = Zb + (Sp & 1) * 49152;
      short8 cf[3];
      #pragma unroll
      for (int m = 0; m < 3; ++m) {
        const char* csrc = (lq < 3) ? (Cf + ((Sp * 3 + m) * 16 + lc) * 48 + lq * 16) : z16;
        cf[m] = *(const short8*)csrc;
      }
      #pragma unroll
      for (int i = 0; i < 8; ++i) {
        int px = 16 * (wave + 8 * i) + lc;
        const char* zsrc = (lq < 3) ? (zb + lq * 16384 + px * 16) : z16;
        short8 zf = *(const short8*)zsrc;
        acc[0][i] = __builtin_amdgcn_mfma_f32_16x16x32_bf16(cf[0], zf, acc[0][i], 0, 0, 0);
        acc[1][i] = __builtin_amdgcn_mfma_f32_16x16x32_bf16(cf[1], zf, acc[1][i], 0, 0, 0);
        acc[2][i] = __builtin_amdgcn_mfma_f32_16x16x32_bf16(cf[2], zf, acc[2][i], 0, 0, 0);
      }
    }
    wg_barrier_lds();
  }

  // ---- epilogue C(5): Zb[1] complete after final barrier ----
  {
    const char* zb = Zb + 1 * 49152;
    short8 cf[3];
    #pragma unroll
    for (int m = 0; m < 3; ++m) {
      const char* csrc = (lq < 3) ? (Cf + ((5 * 3 + m) * 16 + lc) * 48 + lq * 16) : z16;
      cf[m] = *(const short8*)csrc;
    }
    #pragma unroll
    for (int i = 0; i < 8; ++i) {
      int px = 16 * (wave + 8 * i) + lc;
      const char* zsrc = (lq < 3) ? (zb + lq * 16384 + px * 16) : z16;
      short8 zf = *(const short8*)zsrc;
      acc[0][i] = __builtin_amdgcn_mfma_f32_16x16x32_bf16(cf[0], zf, acc[0][i], 0, 0, 0);
      acc[1][i] = __builtin_amdgcn_mfma_f32_16x16x32_bf16(cf[1], zf, acc[1][i], 0, 0, 0);
      acc[2][i] = __builtin_amdgcn_mfma_f32_16x16x32_bf16(cf[2], zf, acc[2][i], 0, 0, 0);
    }
  }

  // ---- epilogue stores (identical R11) ----
  #pragma unroll
  for (int m = 0; m < 3; ++m)
    #pragma unroll
    for (int i = 0; i < 8; ++i) {
      int n = wave + 8 * i;
      size_t rowbase = (((size_t)(b * 48 + 16 * m + 4 * lq)) * 512 + p * 64 + n) * 512
                       + q * 64 + j0 + lc;
      #pragma unroll
      for (int r = 0; r < 4; ++r)
        out[rowbase + (size_t)r * 262144] = acc[m][i][r];
    }
}

extern "C" void kernel_launch(void* const* d_in, const int* in_sizes, int n_in,
                              void* d_out, int out_size, void* d_ws, size_t ws_size,
                              hipStream_t stream) {
  (void)in_sizes; (void)n_in; (void)d_ws; (void)ws_size; (void)out_size;
  const float* x   = (const float*)d_in[0];
  const float* Ws  = (const float*)d_in[1];
  const float* Hsm = (const float*)d_in[2];
  const float* Cs  = (const float*)d_in[3];
  float* out = (float*)d_out;
  (void)hipFuncSetAttribute((const void*)fpb13,
                            hipFuncAttributeMaxDynamicSharedMemorySize, SMEM_BYTES);
  fpb13<<<dim3(1024), dim3(512), SMEM_BYTES, stream>>>(x, Ws, Hsm, Cs, out);
}